// Round 16
// baseline (184.354 us; speedup 1.0000x reference)
//
#include <hip/hip_runtime.h>

typedef unsigned short u16;
typedef unsigned int u32;
typedef unsigned long long u64;
typedef __bf16 v8bf __attribute__((ext_vector_type(8)));
typedef __bf16 v4bf __attribute__((ext_vector_type(4)));
typedef float v4f __attribute__((ext_vector_type(4)));
typedef float v16f __attribute__((ext_vector_type(16)));
typedef u32 v4u __attribute__((ext_vector_type(4)));

#define BB 4
#define TT 2048
#define HH 16
#define DD 1024
// HD = 64

__device__ __forceinline__ u16 f2bf(float f){
  u32 u = __float_as_uint(f);
  u32 r = u + 0x7FFFu + ((u >> 16) & 1u);
  return (u16)(r >> 16);
}
__device__ __forceinline__ float bf2f(u16 h){ return __uint_as_float(((u32)h) << 16); }
__device__ __forceinline__ v16f z16(){
  v16f z;
#pragma unroll
  for (int i = 0; i < 16; i++) z[i] = 0.f;
  return z;
}
__device__ __forceinline__ u32 cvtpk(float lo, float hi){
  u32 d;
  asm("v_cvt_pk_bf16_f32 %0, %1, %2" : "=v"(d) : "v"(lo), "v"(hi));
  return d;
}
__device__ __forceinline__ void swap32(u32 &a, u32 &b){
  asm volatile("v_permlane32_swap_b32 %0, %1" : "+v"(a), "+v"(b));
}

typedef __attribute__((address_space(1))) const void gas_t;
typedef __attribute__((address_space(3))) void las_t;
__device__ __forceinline__ void gl_lds16(const void* g, void* l){
  __builtin_amdgcn_global_load_lds((gas_t*)g, (las_t*)l, 16, 0, 0);
}

// ---------------------------------------------------------------- convert
__global__ __launch_bounds__(256) void k_convert(
    const float* __restrict__ x, const float* __restrict__ wa,
    const float* __restrict__ wp, u16* __restrict__ xb,
    u16* __restrict__ wab, u16* __restrict__ wpb){
  int i = blockIdx.x * 256 + threadIdx.x;
  const int nxq = (BB*TT*DD) / 4;
  const int naq = (3*DD*DD) / 4;
  const float* src; u16* dst; int j;
  if (i < nxq)            { src = x;  dst = xb;  j = i; }
  else if (i < nxq + naq) { src = wa; dst = wab; j = i - nxq; }
  else                    { src = wp; dst = wpb; j = i - nxq - naq; }
  float4 v = reinterpret_cast<const float4*>(src)[j];
  u64 p = (u64)f2bf(v.x) | ((u64)f2bf(v.y) << 16)
        | ((u64)f2bf(v.z) << 32) | ((u64)f2bf(v.w) << 48);
  reinterpret_cast<u64*>(dst)[j] = p;
}

// ---------------------------------------------------------------- GEMM (C = A * Bt^T)
// 128x128 tile, BK=64, 4 waves (2x2 of 64x64), m97-style 2-barrier K-loop.
// Block mapping XCD-chunked. mode 0: RoPE-fused scatter -> q/k [B,H,T,64]
// (Q scaled 0.125*log2e) and V TRANSPOSED vt [B,H,64,T]. mode 1: f32 C.
__global__ __launch_bounds__(256) void k_gemm_bt(
    const u16* __restrict__ A, const u16* __restrict__ Bt,
    const float* __restrict__ rope,
    int M, int N, int K, int mode, float* __restrict__ Cf,
    u16* __restrict__ qo, u16* __restrict__ ko, u16* __restrict__ vo){
  __shared__ char smem[32768];
  char* As = smem;
  char* Bs = smem + 16384;
  const int t = threadIdx.x;
  const int lane = t & 63, w = t >> 6;
  const int c = lane & 15, g = lane >> 4;
  const int nbn = N >> 7;
  const int chunk = gridDim.x >> 3;            // nwg % 8 == 0
  const int swzb = (blockIdx.x & 7) * chunk + (blockIdx.x >> 3);
  const int bm = swzb / nbn, bn = swzb % nbn;
  const long arow0 = (long)bm * 128;
  const long brow0 = (long)bn * 128;
  const int wrow = (w >> 1) * 64, wcol = (w & 1) * 64;

  v4f acc[4][4];
#pragma unroll
  for (int i = 0; i < 4; i++)
#pragma unroll
    for (int j = 0; j < 4; j++){ v4f z = {0.f,0.f,0.f,0.f}; acc[i][j] = z; }

  for (int k0 = 0; k0 < K; k0 += 64){
    __syncthreads();
#pragma unroll
    for (int i = 0; i < 4; i++){
      int slot = t + i * 256;
      int row  = slot >> 3;
      int cb   = (slot & 7) << 4;
      int scb  = cb ^ ((row & 7) << 4);
      gl_lds16((const char*)A  + ((arow0 + row) * (long)K + k0) * 2 + scb,
               As + ((t & 192) + i * 256) * 16);
      gl_lds16((const char*)Bt + ((brow0 + row) * (long)K + k0) * 2 + scb,
               Bs + ((t & 192) + i * 256) * 16);
    }
    __syncthreads();

    v8bf af[4][2], bfr[4][2];
#pragma unroll
    for (int mt = 0; mt < 4; mt++){
      int row = wrow + mt * 16 + c;
      int sw  = (row & 7) << 4;
#pragma unroll
      for (int ks = 0; ks < 2; ks++)
        af[mt][ks] = *(const v8bf*)(As + row * 128 + ((ks * 64 + g * 16) ^ sw));
    }
#pragma unroll
    for (int nt = 0; nt < 4; nt++){
      int row = wcol + nt * 16 + c;
      int sw  = (row & 7) << 4;
#pragma unroll
      for (int ks = 0; ks < 2; ks++)
        bfr[nt][ks] = *(const v8bf*)(Bs + row * 128 + ((ks * 64 + g * 16) ^ sw));
    }
#pragma unroll
    for (int mt = 0; mt < 4; mt++)
#pragma unroll
      for (int nt = 0; nt < 4; nt++)
#pragma unroll
        for (int ks = 0; ks < 2; ks++)
          acc[mt][nt] = __builtin_amdgcn_mfma_f32_16x16x32_bf16(
              af[mt][ks], bfr[nt][ks], acc[mt][nt], 0, 0, 0);
  }

  if (mode == 1){
#pragma unroll
    for (int mt = 0; mt < 4; mt++)
#pragma unroll
      for (int nt = 0; nt < 4; nt++)
#pragma unroll
        for (int r = 0; r < 4; r++){
          long row = arow0 + wrow + mt * 16 + g * 4 + r;
          long col = brow0 + wcol + nt * 16 + c;
          Cf[row * N + col] = acc[mt][nt][r];
        }
  } else {
    // ---- stage rope slice for this tile's 128 t-rows: 128*256B = 32KB
    const int t0 = (int)(arow0 & 2047);
    __syncthreads();                     // all waves done with K-loop LDS
#pragma unroll
    for (int l = 0; l < 8; l++)
      gl_lds16((const char*)rope + (size_t)t0 * 256 + (size_t)(t + l * 256) * 16,
               smem + ((t & 192) + l * 256) * 16);
    __syncthreads();                     // drains vmcnt; all rope rows visible

    const long bb = arow0 >> 11;         // 128-row tile never crosses batch
#pragma unroll
    for (int mt = 0; mt < 4; mt++){
      const int tposb = wrow + mt * 16 + g * 4;      // local t (0..127)
#pragma unroll
      for (int nt = 0; nt < 4; nt++){
        int e    = (int)brow0 + wcol + nt * 16 + c;
        int tsel = e >> 10;
        int hh   = (e >> 6) & 15;
        int d    = e & 63;
        if (tsel == 2){
          // V transposed: vt[((b*H+h)*64+d)*T + t], 4 t-contiguous -> packed
          v4bf pk;
#pragma unroll
          for (int r = 0; r < 4; r++) pk[r] = (__bf16)acc[mt][nt][r];
          *(v4bf*)(vo + (((bb * HH + hh) * 64 + d) << 11) + t0 + tposb) = pk;
        } else {
          const float qs = tsel ? 1.0f : 0.18033688011112042f; // 0.125*log2e
          const int f = d >> 1;
          const bool odd = d & 1;
          u16* dst = tsel ? ko : qo;
          long base = ((bb * HH + hh) * TT + t0 + tposb) * 64 + d;
#pragma unroll
          for (int r = 0; r < 4; r++){
            float v = acc[mt][nt][r];
            float2 cn = *(const float2*)(smem + (tposb + r) * 256 + f * 8);
            float px = __shfl_xor(v, 1, 64);   // even<->odd pair (lane^1)
            float o = odd ? (px * cn.y + v * cn.x) : (v * cn.x - px * cn.y);
            dst[base + (long)r * 64] = f2bf(o * qs);
          }
        }
      }
    }
  }
}

// ---------------------------------------------------------------- flash attention
// Q,K: [B*H, T, 64] bf16 (Q pre-scaled by 0.125*log2e). Vt: [B*H, 64, T] bf16.
// O: [B, T, 1024] bf16.  512 blocks x 256 threads: (head, 256-row q-tile).
// Each wave owns 64 q-rows = TWO 32-row fragment sets processed per staged
// KV tile -> staged-tile events per head drop 272 -> 144 (the r11/r13-measured
// cost driver). Grid 512 = 2 blocks/CU fully resident; bt ordering pairs
// (7-k, k) so co-resident work sums are uniform.
// Swapped QK^T (32x32x16); FIXED-SHIFT softmax (exp2(s-12), exact in P/l);
// P in REGISTERS via cvt_pk + permlane32_swap.
__global__ __launch_bounds__(256) void k_attn(
    const u16* __restrict__ Q, const u16* __restrict__ K,
    const u16* __restrict__ Vt, u16* __restrict__ O){
  __shared__ char smem[16384];
  char* ksm = smem;            // [64 key][128B], XOR-swizzled via source
  char* vsm = smem + 8192;     // [64 d][128B] of V^T, XOR-swizzled via source
  int bx = blockIdx.x;
  int bh = bx & 63;            // same head -> same bx%8 -> same XCD (L2 reuse)
  int bt4 = (bx >> 6) & 3;
  int bt = (bx >> 8) ? bt4 : 7 - bt4;   // rounds pair (7-k, k) per CU slot
  int q0 = bt * 256;
  int b = bh >> 4, h = bh & 15;
  const u16* Qb = Q  + (size_t)bh * TT * 64;
  const u16* Kb = K  + (size_t)bh * TT * 64;
  const u16* Vb = Vt + (size_t)bh * 64 * TT;
  const int t = threadIdx.x, lane = t & 63, w = t >> 6;
  const int c = lane & 31, hi = lane >> 5;
  const int swz = (c & 7) << 4;
  const int wq0 = q0 + w * 64;          // wave's 64 q-rows

  // Q fragments for both 32-row halves: B-layout col=q, k=hi*8+j
  v8bf qf[2][4];
#pragma unroll
  for (int qi = 0; qi < 2; qi++){
    const u16* qrow = Qb + (size_t)(wq0 + qi * 32 + c) * 64 + hi * 8;
#pragma unroll
    for (int kc = 0; kc < 4; kc++) qf[qi][kc] = *(const v8bf*)(qrow + kc * 16);
  }

  float l_[2] = {0.f, 0.f};
  v16f acc[2][2];
#pragma unroll
  for (int qi = 0; qi < 2; qi++){ acc[qi][0] = z16(); acc[qi][1] = z16(); }

  for (int kv0 = 0; kv0 < q0 + 256; kv0 += 64){
    __syncthreads();
#pragma unroll
    for (int i = 0; i < 2; i++){
      int s   = t + i * 256;
      int row = s >> 3;
      int cb  = (s & 7) << 4;
      int scb = cb ^ ((row & 7) << 4);
      gl_lds16((const char*)Kb + (size_t)(kv0 + row) * 128 + scb,
               ksm + ((t & 192) + i * 256) * 16);
      gl_lds16((const char*)Vb + (size_t)row * (TT * 2) + (size_t)kv0 * 2 + scb,
               vsm + ((t & 192) + i * 256) * 16);
    }
    __syncthreads();

#pragma unroll
    for (int qi = 0; qi < 2; qi++){
      const int mq0 = wq0 + qi * 32;        // this fragment-set's first q-row
      if (kv0 > mq0 + 31) continue;         // fully masked for this half
      // S^T = K * Q^T : lane holds S[key=kv0+s*32+crow(r,hi)][q=mq0+c]
      v16f s0 = z16(), s1 = z16();
      __builtin_amdgcn_s_setprio(1);
#pragma unroll
      for (int kc = 0; kc < 4; kc++){
        int off = (kc * 32 + hi * 16) ^ swz;
        v8bf a0 = *(const v8bf*)(ksm + c * 128 + off);
        v8bf a1 = *(const v8bf*)(ksm + (32 + c) * 128 + off);
        s0 = __builtin_amdgcn_mfma_f32_32x32x16_bf16(a0, qf[qi][kc], s0, 0, 0, 0);
        s1 = __builtin_amdgcn_mfma_f32_32x32x16_bf16(a1, qf[qi][kc], s1, 0, 0, 0);
      }
      __builtin_amdgcn_s_setprio(0);
      // causal mask (diagonal tiles only)
      if (kv0 + 63 > mq0){
        int q = mq0 + c;
#pragma unroll
        for (int r = 0; r < 16; r++){
          int crow = (r & 3) + 8 * (r >> 2) + 4 * hi;
          if (kv0 + crow > q)      s0[r] = -1e30f;
          if (kv0 + 32 + crow > q) s1[r] = -1e30f;
        }
      }
      // fixed-shift softmax: P = exp2(s - 12); masked -> 0.
      float sum = 0.f;
#pragma unroll
      for (int r = 0; r < 16; r++){
        float p0 = __builtin_amdgcn_exp2f(s0[r] - 12.0f);
        float p1 = __builtin_amdgcn_exp2f(s1[r] - 12.0f);
        s0[r] = p0; s1[r] = p1;
        sum += p0 + p1;
      }
      sum += __shfl_xor(sum, 32, 64);
      l_[qi] += sum;
      // P -> registers: cvt_pk pairs + permlane32_swap redistribution.
      v8bf pbf[4];
      {
        u32 wd[16];
#pragma unroll
        for (int i = 0; i < 8; i++) wd[i]     = cvtpk(s0[2*i], s0[2*i+1]);
#pragma unroll
        for (int i = 0; i < 8; i++) wd[8 + i] = cvtpk(s1[2*i], s1[2*i+1]);
        swap32(wd[0], wd[2]);  swap32(wd[1], wd[3]);
        swap32(wd[4], wd[6]);  swap32(wd[5], wd[7]);
        swap32(wd[8], wd[10]); swap32(wd[9], wd[11]);
        swap32(wd[12], wd[14]); swap32(wd[13], wd[15]);
        v4u u0 = {wd[0], wd[1], wd[2], wd[3]};
        v4u u1 = {wd[4], wd[5], wd[6], wd[7]};
        v4u u2 = {wd[8], wd[9], wd[10], wd[11]};
        v4u u3 = {wd[12], wd[13], wd[14], wd[15]};
        pbf[0] = __builtin_bit_cast(v8bf, u0);
        pbf[1] = __builtin_bit_cast(v8bf, u1);
        pbf[2] = __builtin_bit_cast(v8bf, u2);
        pbf[3] = __builtin_bit_cast(v8bf, u3);
      }
      // O^T += Vt * P
      __builtin_amdgcn_s_setprio(1);
#pragma unroll
      for (int kc = 0; kc < 4; kc++){
        int off = (kc * 32 + hi * 16) ^ swz;
        v8bf va0 = *(const v8bf*)(vsm + c * 128 + off);
        v8bf va1 = *(const v8bf*)(vsm + (32 + c) * 128 + off);
        acc[qi][0] = __builtin_amdgcn_mfma_f32_32x32x16_bf16(va0, pbf[kc], acc[qi][0], 0, 0, 0);
        acc[qi][1] = __builtin_amdgcn_mfma_f32_32x32x16_bf16(va1, pbf[kc], acc[qi][1], 0, 0, 0);
      }
      __builtin_amdgcn_s_setprio(0);
    }
  }

  // epilogue: lane holds O[q=mq0+c][d=ds*32+crow(r,hi)]; 1/l lane-local
#pragma unroll
  for (int qi = 0; qi < 2; qi++){
    float inv = __builtin_amdgcn_rcpf(l_[qi]);
    int q = wq0 + qi * 32 + c;
    u16* orow = O + ((size_t)(b * TT + q)) * DD + h * 64;
#pragma unroll
    for (int q4 = 0; q4 < 4; q4++){
      v4bf o0, o1;
#pragma unroll
      for (int j = 0; j < 4; j++){
        o0[j] = (__bf16)(acc[qi][0][q4 * 4 + j] * inv);
        o1[j] = (__bf16)(acc[qi][1][q4 * 4 + j] * inv);
      }
      *(v4bf*)(orow + q4 * 8 + hi * 4)      = o0;
      *(v4bf*)(orow + 32 + q4 * 8 + hi * 4) = o1;
    }
  }
}

// ---------------------------------------------------------------- launch
extern "C" void kernel_launch(void* const* d_in, const int* in_sizes, int n_in,
                              void* d_out, int out_size, void* d_ws, size_t ws_size,
                              hipStream_t stream){
  const float* x    = (const float*)d_in[0];
  const float* rope = (const float*)d_in[1];
  const float* Wa   = (const float*)d_in[3];
  const float* Wp   = (const float*)d_in[4];

  char* ws = (char*)d_ws;
  u16* xb  = (u16*)(ws);                    // 16 MB (dead after qkv gemm)
  u16* wab = (u16*)(ws + (16u << 20));      // 6 MB
  u16* wpb = (u16*)(ws + (22u << 20));      // 2 MB
  u16* qb  = (u16*)(ws + (24u << 20));      // 16 MB
  u16* kb  = (u16*)(ws + (40u << 20));      // 16 MB
  u16* vtb = (u16*)(ws + (56u << 20));      // 16 MB (V stored transposed)
  u16* ob  = xb;                            // reuse for O

  k_convert<<<dim3(12288), dim3(256), 0, stream>>>(x, Wa, Wp, xb, wab, wpb);
  k_gemm_bt<<<dim3(24 * 64), dim3(256), 0, stream>>>(
      xb, wab, rope, 8192, 3072, 1024, 0, nullptr, qb, kb, vtb);
  k_attn<<<dim3(512), dim3(256), 0, stream>>>(qb, kb, vtb, ob);
  k_gemm_bt<<<dim3(8 * 64), dim3(256), 0, stream>>>(
      ob, wpb, nullptr, 8192, 1024, 1024, 1, (float*)d_out,
      nullptr, nullptr, nullptr);
}

// Round 18
// 164.894 us; speedup vs baseline: 1.1180x; 1.1180x over previous
//
#include <hip/hip_runtime.h>

typedef unsigned short u16;
typedef unsigned int u32;
typedef unsigned long long u64;
typedef __bf16 v8bf __attribute__((ext_vector_type(8)));
typedef __bf16 v4bf __attribute__((ext_vector_type(4)));
typedef float v4f __attribute__((ext_vector_type(4)));
typedef float v16f __attribute__((ext_vector_type(16)));
typedef u32 v4u __attribute__((ext_vector_type(4)));

#define BB 4
#define TT 2048
#define HH 16
#define DD 1024
// HD = 64

__device__ __forceinline__ u16 f2bf(float f){
  u32 u = __float_as_uint(f);
  u32 r = u + 0x7FFFu + ((u >> 16) & 1u);
  return (u16)(r >> 16);
}
__device__ __forceinline__ float bf2f(u16 h){ return __uint_as_float(((u32)h) << 16); }
__device__ __forceinline__ v16f z16(){
  v16f z;
#pragma unroll
  for (int i = 0; i < 16; i++) z[i] = 0.f;
  return z;
}
__device__ __forceinline__ u32 cvtpk(float lo, float hi){
  u32 d;
  asm("v_cvt_pk_bf16_f32 %0, %1, %2" : "=v"(d) : "v"(lo), "v"(hi));
  return d;
}
__device__ __forceinline__ void swap32(u32 &a, u32 &b){
  asm volatile("v_permlane32_swap_b32 %0, %1" : "+v"(a), "+v"(b));
}

typedef __attribute__((address_space(1))) const void gas_t;
typedef __attribute__((address_space(3))) void las_t;
__device__ __forceinline__ void gl_lds16(const void* g, void* l){
  __builtin_amdgcn_global_load_lds((gas_t*)g, (las_t*)l, 16, 0, 0);
}

// ---------------------------------------------------------------- convert
__global__ __launch_bounds__(256) void k_convert(
    const float* __restrict__ x, const float* __restrict__ wa,
    const float* __restrict__ wp, u16* __restrict__ xb,
    u16* __restrict__ wab, u16* __restrict__ wpb){
  int i = blockIdx.x * 256 + threadIdx.x;
  const int nxq = (BB*TT*DD) / 4;
  const int naq = (3*DD*DD) / 4;
  const float* src; u16* dst; int j;
  if (i < nxq)            { src = x;  dst = xb;  j = i; }
  else if (i < nxq + naq) { src = wa; dst = wab; j = i - nxq; }
  else                    { src = wp; dst = wpb; j = i - nxq - naq; }
  float4 v = reinterpret_cast<const float4*>(src)[j];
  u64 p = (u64)f2bf(v.x) | ((u64)f2bf(v.y) << 16)
        | ((u64)f2bf(v.z) << 32) | ((u64)f2bf(v.w) << 48);
  reinterpret_cast<u64*>(dst)[j] = p;
}

// ---------------------------------------------------------------- GEMM (C = A * Bt^T)
// 128x128 tile, BK=64, 4 waves (2x2 of 64x64), m97-style 2-barrier K-loop.
// Block mapping XCD-chunked. mode 0: RoPE-fused scatter -> q/k [B,H,T,64]
// (Q scaled 0.125*log2e) and V TRANSPOSED vt [B,H,64,T]. mode 1: f32 C.
__global__ __launch_bounds__(256) void k_gemm_bt(
    const u16* __restrict__ A, const u16* __restrict__ Bt,
    const float* __restrict__ rope,
    int M, int N, int K, int mode, float* __restrict__ Cf,
    u16* __restrict__ qo, u16* __restrict__ ko, u16* __restrict__ vo){
  __shared__ char smem[32768];
  char* As = smem;
  char* Bs = smem + 16384;
  const int t = threadIdx.x;
  const int lane = t & 63, w = t >> 6;
  const int c = lane & 15, g = lane >> 4;
  const int nbn = N >> 7;
  const int chunk = gridDim.x >> 3;            // nwg % 8 == 0
  const int swzb = (blockIdx.x & 7) * chunk + (blockIdx.x >> 3);
  const int bm = swzb / nbn, bn = swzb % nbn;
  const long arow0 = (long)bm * 128;
  const long brow0 = (long)bn * 128;
  const int wrow = (w >> 1) * 64, wcol = (w & 1) * 64;

  v4f acc[4][4];
#pragma unroll
  for (int i = 0; i < 4; i++)
#pragma unroll
    for (int j = 0; j < 4; j++){ v4f z = {0.f,0.f,0.f,0.f}; acc[i][j] = z; }

  for (int k0 = 0; k0 < K; k0 += 64){
    __syncthreads();
#pragma unroll
    for (int i = 0; i < 4; i++){
      int slot = t + i * 256;
      int row  = slot >> 3;
      int cb   = (slot & 7) << 4;
      int scb  = cb ^ ((row & 7) << 4);
      gl_lds16((const char*)A  + ((arow0 + row) * (long)K + k0) * 2 + scb,
               As + ((t & 192) + i * 256) * 16);
      gl_lds16((const char*)Bt + ((brow0 + row) * (long)K + k0) * 2 + scb,
               Bs + ((t & 192) + i * 256) * 16);
    }
    __syncthreads();

    v8bf af[4][2], bfr[4][2];
#pragma unroll
    for (int mt = 0; mt < 4; mt++){
      int row = wrow + mt * 16 + c;
      int sw  = (row & 7) << 4;
#pragma unroll
      for (int ks = 0; ks < 2; ks++)
        af[mt][ks] = *(const v8bf*)(As + row * 128 + ((ks * 64 + g * 16) ^ sw));
    }
#pragma unroll
    for (int nt = 0; nt < 4; nt++){
      int row = wcol + nt * 16 + c;
      int sw  = (row & 7) << 4;
#pragma unroll
      for (int ks = 0; ks < 2; ks++)
        bfr[nt][ks] = *(const v8bf*)(Bs + row * 128 + ((ks * 64 + g * 16) ^ sw));
    }
#pragma unroll
    for (int mt = 0; mt < 4; mt++)
#pragma unroll
      for (int nt = 0; nt < 4; nt++)
#pragma unroll
        for (int ks = 0; ks < 2; ks++)
          acc[mt][nt] = __builtin_amdgcn_mfma_f32_16x16x32_bf16(
              af[mt][ks], bfr[nt][ks], acc[mt][nt], 0, 0, 0);
  }

  if (mode == 1){
#pragma unroll
    for (int mt = 0; mt < 4; mt++)
#pragma unroll
      for (int nt = 0; nt < 4; nt++)
#pragma unroll
        for (int r = 0; r < 4; r++){
          long row = arow0 + wrow + mt * 16 + g * 4 + r;
          long col = brow0 + wcol + nt * 16 + c;
          Cf[row * N + col] = acc[mt][nt][r];
        }
  } else {
    // ---- stage rope slice for this tile's 128 t-rows: 128*256B = 32KB
    const int t0 = (int)(arow0 & 2047);
    __syncthreads();                     // all waves done with K-loop LDS
#pragma unroll
    for (int l = 0; l < 8; l++)
      gl_lds16((const char*)rope + (size_t)t0 * 256 + (size_t)(t + l * 256) * 16,
               smem + ((t & 192) + l * 256) * 16);
    __syncthreads();                     // drains vmcnt; all rope rows visible

    const long bb = arow0 >> 11;         // 128-row tile never crosses batch
#pragma unroll
    for (int mt = 0; mt < 4; mt++){
      const int tposb = wrow + mt * 16 + g * 4;      // local t (0..127)
#pragma unroll
      for (int nt = 0; nt < 4; nt++){
        int e    = (int)brow0 + wcol + nt * 16 + c;
        int tsel = e >> 10;
        int hh   = (e >> 6) & 15;
        int d    = e & 63;
        if (tsel == 2){
          // V transposed: vt[((b*H+h)*64+d)*T + t], 4 t-contiguous -> packed
          v4bf pk;
#pragma unroll
          for (int r = 0; r < 4; r++) pk[r] = (__bf16)acc[mt][nt][r];
          *(v4bf*)(vo + (((bb * HH + hh) * 64 + d) << 11) + t0 + tposb) = pk;
        } else {
          const float qs = tsel ? 1.0f : 0.18033688011112042f; // 0.125*log2e
          const int f = d >> 1;
          const bool odd = d & 1;
          u16* dst = tsel ? ko : qo;
          long base = ((bb * HH + hh) * TT + t0 + tposb) * 64 + d;
#pragma unroll
          for (int r = 0; r < 4; r++){
            float v = acc[mt][nt][r];
            float2 cn = *(const float2*)(smem + (tposb + r) * 256 + f * 8);
            float px = __shfl_xor(v, 1, 64);   // even<->odd pair (lane^1)
            float o = odd ? (px * cn.y + v * cn.x) : (v * cn.x - px * cn.y);
            dst[base + (long)r * 64] = f2bf(o * qs);
          }
        }
      }
    }
  }
}

// ---------------------------------------------------------------- flash attention
// Q,K: [B*H, T, 64] bf16 (Q pre-scaled by 0.125*log2e). Vt: [B*H, 64, T] bf16.
// O: [B, T, 1024] bf16.  1024 blocks x 256 threads: (head, 128-row q-tile),
// heavy-first. Swapped QK^T (32x32x16): lane owns q-col; softmax lane-local.
// FIXED-SHIFT softmax: scores are log2-domain ~N(0,~1.5); P = exp2(s - 12)
// is exact softmax (scale cancels in P/l) for any |s| < ~120 — no max tree,
// no rescale, no m state. P in REGISTERS via cvt_pk + permlane32_swap.
__global__ __launch_bounds__(256) void k_attn(
    const u16* __restrict__ Q, const u16* __restrict__ K,
    const u16* __restrict__ Vt, u16* __restrict__ O){
  __shared__ char smem[16384];
  char* ksm = smem;            // [64 key][128B], XOR-swizzled via source
  char* vsm = smem + 8192;     // [64 d][128B] of V^T, XOR-swizzled via source
  int bx = blockIdx.x;
  int bh = bx & 63;            // same head -> same bx%8 -> same XCD (L2 reuse)
  int bt = 15 - (bx >> 6);     // heavy q-tiles first
  int q0 = bt * 128;
  int b = bh >> 4, h = bh & 15;
  const u16* Qb = Q  + (size_t)bh * TT * 64;
  const u16* Kb = K  + (size_t)bh * TT * 64;
  const u16* Vb = Vt + (size_t)bh * 64 * TT;
  const int t = threadIdx.x, lane = t & 63, w = t >> 6;
  const int c = lane & 31, hi = lane >> 5;
  const int swz = (c & 7) << 4;
  const int wq0 = q0 + w * 32;

  // Q fragments: B-layout col=q, k=hi*8+j; 4 chunks of K-dim 16
  v8bf qf[4];
  {
    const u16* qrow = Qb + (size_t)(wq0 + c) * 64 + hi * 8;
#pragma unroll
    for (int kc = 0; kc < 4; kc++) qf[kc] = *(const v8bf*)(qrow + kc * 16);
  }

  float l_ = 0.f;
  v16f accO0 = z16(), accO1 = z16();

  for (int kv0 = 0; kv0 < q0 + 128; kv0 += 64){
    __syncthreads();
#pragma unroll
    for (int i = 0; i < 2; i++){
      int s   = t + i * 256;
      int row = s >> 3;
      int cb  = (s & 7) << 4;
      int scb = cb ^ ((row & 7) << 4);
      gl_lds16((const char*)Kb + (size_t)(kv0 + row) * 128 + scb,
               ksm + ((t & 192) + i * 256) * 16);
      gl_lds16((const char*)Vb + (size_t)row * (TT * 2) + (size_t)kv0 * 2 + scb,
               vsm + ((t & 192) + i * 256) * 16);
    }
    __syncthreads();

    if (kv0 <= wq0 + 31){
      // S^T = K * Q^T : lane holds S[key=kv0+s*32+crow(r,hi)][q=wq0+c]
      v16f s0 = z16(), s1 = z16();
      __builtin_amdgcn_s_setprio(1);
#pragma unroll
      for (int kc = 0; kc < 4; kc++){
        int off = (kc * 32 + hi * 16) ^ swz;
        v8bf a0 = *(const v8bf*)(ksm + c * 128 + off);
        v8bf a1 = *(const v8bf*)(ksm + (32 + c) * 128 + off);
        s0 = __builtin_amdgcn_mfma_f32_32x32x16_bf16(a0, qf[kc], s0, 0, 0, 0);
        s1 = __builtin_amdgcn_mfma_f32_32x32x16_bf16(a1, qf[kc], s1, 0, 0, 0);
      }
      __builtin_amdgcn_s_setprio(0);
      // causal mask (diagonal tiles only)
      if (kv0 + 63 > wq0){
        int q = wq0 + c;
#pragma unroll
        for (int r = 0; r < 16; r++){
          int crow = (r & 3) + 8 * (r >> 2) + 4 * hi;
          if (kv0 + crow > q)      s0[r] = -1e30f;
          if (kv0 + 32 + crow > q) s1[r] = -1e30f;
        }
      }
      // fixed-shift softmax: P = exp2(s - 12); masked -> exp2(-inf) = 0.
      float sum = 0.f;
#pragma unroll
      for (int r = 0; r < 16; r++){
        float p0 = __builtin_amdgcn_exp2f(s0[r] - 12.0f);
        float p1 = __builtin_amdgcn_exp2f(s1[r] - 12.0f);
        s0[r] = p0; s1[r] = p1;
        sum += p0 + p1;
      }
      sum += __shfl_xor(sum, 32, 64);
      l_ += sum;
      // P -> registers: cvt_pk pairs + permlane32_swap redistribution.
      v8bf pbf[4];
      {
        u32 wd[16];
#pragma unroll
        for (int i = 0; i < 8; i++) wd[i]     = cvtpk(s0[2*i], s0[2*i+1]);
#pragma unroll
        for (int i = 0; i < 8; i++) wd[8 + i] = cvtpk(s1[2*i], s1[2*i+1]);
        swap32(wd[0], wd[2]);  swap32(wd[1], wd[3]);
        swap32(wd[4], wd[6]);  swap32(wd[5], wd[7]);
        swap32(wd[8], wd[10]); swap32(wd[9], wd[11]);
        swap32(wd[12], wd[14]); swap32(wd[13], wd[15]);
        v4u u0 = {wd[0], wd[1], wd[2], wd[3]};
        v4u u1 = {wd[4], wd[5], wd[6], wd[7]};
        v4u u2 = {wd[8], wd[9], wd[10], wd[11]};
        v4u u3 = {wd[12], wd[13], wd[14], wd[15]};
        pbf[0] = __builtin_bit_cast(v8bf, u0);
        pbf[1] = __builtin_bit_cast(v8bf, u1);
        pbf[2] = __builtin_bit_cast(v8bf, u2);
        pbf[3] = __builtin_bit_cast(v8bf, u3);
      }
      // O^T += Vt * P
      __builtin_amdgcn_s_setprio(1);
#pragma unroll
      for (int kc = 0; kc < 4; kc++){
        int off = (kc * 32 + hi * 16) ^ swz;
        v8bf va0 = *(const v8bf*)(vsm + c * 128 + off);
        v8bf va1 = *(const v8bf*)(vsm + (32 + c) * 128 + off);
        accO0 = __builtin_amdgcn_mfma_f32_32x32x16_bf16(va0, pbf[kc], accO0, 0, 0, 0);
        accO1 = __builtin_amdgcn_mfma_f32_32x32x16_bf16(va1, pbf[kc], accO1, 0, 0, 0);
      }
      __builtin_amdgcn_s_setprio(0);
    }
  }

  // epilogue: lane holds O[q=wq0+c][d=ds*32+crow(r,hi)]; 1/l lane-local
  float inv = __builtin_amdgcn_rcpf(l_);
  int q = wq0 + c;
  u16* orow = O + ((size_t)(b * TT + q)) * DD + h * 64;
#pragma unroll
  for (int q4 = 0; q4 < 4; q4++){
    v4bf o0, o1;
#pragma unroll
    for (int j = 0; j < 4; j++){
      o0[j] = (__bf16)(accO0[q4 * 4 + j] * inv);
      o1[j] = (__bf16)(accO1[q4 * 4 + j] * inv);
    }
    *(v4bf*)(orow + q4 * 8 + hi * 4)      = o0;
    *(v4bf*)(orow + 32 + q4 * 8 + hi * 4) = o1;
  }
}

// ---------------------------------------------------------------- launch
extern "C" void kernel_launch(void* const* d_in, const int* in_sizes, int n_in,
                              void* d_out, int out_size, void* d_ws, size_t ws_size,
                              hipStream_t stream){
  const float* x    = (const float*)d_in[0];
  const float* rope = (const float*)d_in[1];
  const float* Wa   = (const float*)d_in[3];
  const float* Wp   = (const float*)d_in[4];

  char* ws = (char*)d_ws;
  u16* xb  = (u16*)(ws);                    // 16 MB (dead after qkv gemm)
  u16* wab = (u16*)(ws + (16u << 20));      // 6 MB
  u16* wpb = (u16*)(ws + (22u << 20));      // 2 MB
  u16* qb  = (u16*)(ws + (24u << 20));      // 16 MB
  u16* kb  = (u16*)(ws + (40u << 20));      // 16 MB
  u16* vtb = (u16*)(ws + (56u << 20));      // 16 MB (V stored transposed)
  u16* ob  = xb;                            // reuse for O

  k_convert<<<dim3(12288), dim3(256), 0, stream>>>(x, Wa, Wp, xb, wab, wpb);
  k_gemm_bt<<<dim3(24 * 64), dim3(256), 0, stream>>>(
      xb, wab, rope, 8192, 3072, 1024, 0, nullptr, qb, kb, vtb);
  k_attn<<<dim3(1024), dim3(256), 0, stream>>>(qb, kb, vtb, ob);
  k_gemm_bt<<<dim3(8 * 64), dim3(256), 0, stream>>>(
      ob, wpb, nullptr, 8192, 1024, 1024, 1, (float*)d_out,
      nullptr, nullptr, nullptr);
}